// Round 1
// baseline (30.624 us; speedup 1.0000x reference)
//
#include <hip/hip_runtime.h>
#include <hip/hip_bf16.h>
#include <math.h>

#define EPS 1e-10f

// Kernel 1: precompute logE[j] = log(exponential[j] + EPS) once (V elements).
__global__ __launch_bounds__(256) void logE_kernel(const float* __restrict__ e,
                                                   float* __restrict__ logE,
                                                   int V) {
    int i = blockIdx.x * blockDim.x + threadIdx.x;
    if (i < V) logE[i] = logf(e[i] + EPS);
}

// Kernel 2: one block per row. Streaming argmax of
//   greedy row:   logits[j]
//   sampled row:  logits[j] * (1/t) - logE[j]
// (monotone-equivalent to softmax(logits/t)/(E+eps) argmax).
template <bool PRECOMP>
__global__ __launch_bounds__(1024) void sampler_kernel(const float* __restrict__ logits,
                                                       const float* __restrict__ temps,
                                                       const float* __restrict__ noise, // logE if PRECOMP, else raw E
                                                       int* __restrict__ out,
                                                       int V) {
    const int row = blockIdx.x;
    const float t = temps[row];                 // uniform across block
    const bool greedy = (t == 0.0f);
    const float inv_t = greedy ? 1.0f : (1.0f / t);

    const float4* rl4 = reinterpret_cast<const float4*>(logits + (size_t)row * (size_t)V);
    const float4* n4  = reinterpret_cast<const float4*>(noise);

    float best = -INFINITY;
    int   bidx = 0x7fffffff;

    const int nvec = V >> 2;  // V % 4 == 0 (128000)

    if (greedy) {
        for (int i = threadIdx.x; i < nvec; i += blockDim.x) {
            float4 l = rl4[i];
            int base = i << 2;
            if (l.x > best) { best = l.x; bidx = base;     }
            if (l.y > best) { best = l.y; bidx = base + 1; }
            if (l.z > best) { best = l.z; bidx = base + 2; }
            if (l.w > best) { best = l.w; bidx = base + 3; }
        }
    } else {
        for (int i = threadIdx.x; i < nvec; i += blockDim.x) {
            float4 l = rl4[i];
            float4 g = n4[i];
            float g0, g1, g2, g3;
            if (PRECOMP) {
                g0 = g.x; g1 = g.y; g2 = g.z; g3 = g.w;
            } else {
                g0 = logf(g.x + EPS); g1 = logf(g.y + EPS);
                g2 = logf(g.z + EPS); g3 = logf(g.w + EPS);
            }
            float s0 = fmaf(l.x, inv_t, -g0);
            float s1 = fmaf(l.y, inv_t, -g1);
            float s2 = fmaf(l.z, inv_t, -g2);
            float s3 = fmaf(l.w, inv_t, -g3);
            int base = i << 2;
            if (s0 > best) { best = s0; bidx = base;     }
            if (s1 > best) { best = s1; bidx = base + 1; }
            if (s2 > best) { best = s2; bidx = base + 2; }
            if (s3 > best) { best = s3; bidx = base + 3; }
        }
    }

    // Wave-level reduce (wave = 64 lanes on CDNA!). Prefer lower index on ties.
    #pragma unroll
    for (int off = 32; off >= 1; off >>= 1) {
        float ov = __shfl_down(best, off);
        int   oi = __shfl_down(bidx, off);
        if (ov > best || (ov == best && oi < bidx)) { best = ov; bidx = oi; }
    }

    __shared__ float sv[16];
    __shared__ int   si[16];
    const int wid  = threadIdx.x >> 6;
    const int lane = threadIdx.x & 63;
    const int nw   = blockDim.x >> 6;
    if (lane == 0) { sv[wid] = best; si[wid] = bidx; }
    __syncthreads();

    if (wid == 0) {
        best = (lane < nw) ? sv[lane] : -INFINITY;
        bidx = (lane < nw) ? si[lane] : 0x7fffffff;
        #pragma unroll
        for (int off = 8; off >= 1; off >>= 1) {
            float ov = __shfl_down(best, off);
            int   oi = __shfl_down(bidx, off);
            if (ov > best || (ov == best && oi < bidx)) { best = ov; bidx = oi; }
        }
        if (lane == 0) out[row] = bidx;
    }
}

extern "C" void kernel_launch(void* const* d_in, const int* in_sizes, int n_in,
                              void* d_out, int out_size, void* d_ws, size_t ws_size,
                              hipStream_t stream) {
    const float* logits = (const float*)d_in[0];
    const float* temps  = (const float*)d_in[1];
    const float* expo   = (const float*)d_in[2];
    int*         out    = (int*)d_out;

    const int B = in_sizes[1];
    const int V = in_sizes[2];

    if (ws_size >= (size_t)V * sizeof(float)) {
        float* logE = (float*)d_ws;
        logE_kernel<<<(V + 255) / 256, 256, 0, stream>>>(expo, logE, V);
        sampler_kernel<true><<<B, 1024, 0, stream>>>(logits, temps, logE, out, V);
    } else {
        // Fallback: compute log on the fly (no workspace needed).
        sampler_kernel<false><<<B, 1024, 0, stream>>>(logits, temps, expo, out, V);
    }
}